// Round 1
// baseline (738.353 us; speedup 1.0000x reference)
//
#include <hip/hip_runtime.h>
#include <math.h>

static constexpr int Bz = 8;
static constexpr int Lz = 2048;
static constexpr int Cz = 512;
static constexpr int CRz = 128;
static constexpr int DHz = 256;
static constexpr int MT = Bz * Lz;           // 16384 rows
static constexpr float EPSz = 1e-5f;

// ---------------------------------------------------------------------------
// P: fold BN params (alpha/beta) for pw + dw branches; compute Q const vector
// ---------------------------------------------------------------------------
__global__ __launch_bounds__(256) void prep_kernel(
    const float* __restrict__ pw_b, const float* __restrict__ pw_g,
    const float* __restrict__ pw_bb, const float* __restrict__ pw_m,
    const float* __restrict__ pw_v,
    const float* __restrict__ dw_b, const float* __restrict__ dw_g,
    const float* __restrict__ dw_bb, const float* __restrict__ dw_m,
    const float* __restrict__ dw_v,
    const float* __restrict__ df_ln_b, const float* __restrict__ wq,
    const float* __restrict__ bq,
    float* __restrict__ pwA, float* __restrict__ pwB,
    float* __restrict__ dwA, float* __restrict__ dwB,
    float* __restrict__ qc) {
  const int blk = blockIdx.x;
  const int t = threadIdx.x;
  if (blk == 0) {
    for (int c = t; c < Cz; c += 256) {
      float inv = rsqrtf(pw_v[c] + EPSz);
      float a = pw_g[c] * inv;
      float bb = pw_bb[c] - pw_m[c] * a;
      pwA[c] = a;
      pwB[c] = pw_b[c] * a + bb;
    }
  } else if (blk <= 4) {
    const int i = blk - 1;
    for (int c = t; c < Cz; c += 256) {
      int idx = i * Cz + c;
      float inv = rsqrtf(dw_v[idx] + EPSz);
      float a = dw_g[idx] * inv;
      float bb = dw_bb[idx] - dw_m[idx] * a;
      dwA[idx] = a;
      dwB[idx] = dw_b[idx] * a + bb;
    }
  } else {
    // Q = df_ln_b @ wq.T + bq  (D == df_ln_b analytically: diff_feat is
    // channel-constant so its LayerNorm collapses to the bias)
    if (t < DHz) {
      float s = bq[t];
      const float* w = wq + (size_t)t * Cz;
      for (int c = 0; c < Cz; c++) s += df_ln_b[c] * w[c];
      qc[t] = s;
    }
  }
}

// ---------------------------------------------------------------------------
// A: pointwise conv GEMM  xpw[b,o,l] = relu(alpha[o]*sum_c W[o,c]x[b,l,c]+beta[o])
// grid (L/64, C/64, B), 256 thr, 64x64 tile, 4x4 per thread
// ---------------------------------------------------------------------------
__global__ __launch_bounds__(256) void pw_gemm_kernel(
    const float* __restrict__ x, const float* __restrict__ W,
    const float* __restrict__ alpha, const float* __restrict__ beta,
    float* __restrict__ xpw) {
  __shared__ float sW[16][68];
  __shared__ float sX[16][68];
  const int l0 = blockIdx.x * 64;
  const int o0 = blockIdx.y * 64;
  const int b = blockIdx.z;
  const int t = threadIdx.x;
  const int tn = t & 15, tm = t >> 4;
  const int lrow = t >> 2, lk = (t & 3) * 4;
  float acc[4][4] = {};
  const float* wp = W + (size_t)(o0 + lrow) * Cz + lk;
  const float* xp = x + ((size_t)b * Lz + l0 + lrow) * Cz + lk;
  for (int k0 = 0; k0 < Cz; k0 += 16) {
    float4 w4 = *(const float4*)(wp + k0);
    float4 x4 = *(const float4*)(xp + k0);
    __syncthreads();
    sW[lk + 0][lrow] = w4.x; sW[lk + 1][lrow] = w4.y;
    sW[lk + 2][lrow] = w4.z; sW[lk + 3][lrow] = w4.w;
    sX[lk + 0][lrow] = x4.x; sX[lk + 1][lrow] = x4.y;
    sX[lk + 2][lrow] = x4.z; sX[lk + 3][lrow] = x4.w;
    __syncthreads();
#pragma unroll
    for (int k = 0; k < 16; k++) {
      float a[4], bb[4];
      *(float4*)a = *(const float4*)&sW[k][tm * 4];
      *(float4*)bb = *(const float4*)&sX[k][tn * 4];
#pragma unroll
      for (int m = 0; m < 4; m++)
#pragma unroll
        for (int n = 0; n < 4; n++) acc[m][n] += a[m] * bb[n];
    }
  }
#pragma unroll
  for (int m = 0; m < 4; m++) {
    const int o = o0 + tm * 4 + m;
    const float av = alpha[o], bt = beta[o];
    float4 r;
    r.x = fmaxf(acc[m][0] * av + bt, 0.f);
    r.y = fmaxf(acc[m][1] * av + bt, 0.f);
    r.z = fmaxf(acc[m][2] * av + bt, 0.f);
    r.w = fmaxf(acc[m][3] * av + bt, 0.f);
    *(float4*)(xpw + ((size_t)(b * Cz + o)) * Lz + l0 + tn * 4) = r;
  }
}

// ---------------------------------------------------------------------------
// B: depthwise conv (4 branches) + bias/BN/ReLU folded + per-row sum
// grid 4*B*C blocks, 256 thr; block = one (branch,b,c) row of length L
// ---------------------------------------------------------------------------
__global__ __launch_bounds__(256) void dw_conv_kernel(
    const float* __restrict__ xpw,
    const float* __restrict__ w0, const float* __restrict__ w1,
    const float* __restrict__ w2, const float* __restrict__ w3,
    const float* __restrict__ dwA, const float* __restrict__ dwB,
    float* __restrict__ y, float* __restrict__ ysum) {
  __shared__ float row[Lz];
  __shared__ float wts[20];
  __shared__ float wsum[4];
  const int bx = blockIdx.x;
  const int i = bx >> 12;            // /(B*C)=4096
  const int rem = bx & 4095;
  const int b = rem >> 9;
  const int c = rem & 511;
  const int ks[4] = {3, 7, 15, 20};
  const int k = ks[i];
  const int p = (k - 1) >> 1;
  const int valid = (i == 3) ? (Lz - 1) : Lz;
  const float* w = (i == 0 ? w0 : i == 1 ? w1 : i == 2 ? w2 : w3) + c * k;
  const int t = threadIdx.x;
  const float* src = xpw + ((size_t)(b * Cz + c)) * Lz;
  for (int idx = t; idx < Lz / 4; idx += 256)
    ((float4*)row)[idx] = ((const float4*)src)[idx];
  if (t < k) wts[t] = w[t];
  __syncthreads();
  const float a = dwA[i * Cz + c], bb = dwB[i * Cz + c];
  float* dst = y + ((size_t)((i * Bz + b) * Cz + c)) * Lz;
  float psum = 0.f;
  for (int s = 0; s < 8; s++) {
    const int l = t + s * 256;
    float acc = 0.f;
    for (int j = 0; j < k; j++) {
      const int xi = l + j - p;
      if (xi >= 0 && xi < Lz) acc += wts[j] * row[xi];
    }
    float v = fmaxf(acc * a + bb, 0.f);
    if (l >= valid) v = 0.f;
    dst[l] = v;
    psum += v;
  }
  for (int off = 32; off > 0; off >>= 1) psum += __shfl_down(psum, off, 64);
  if ((t & 63) == 0) wsum[t >> 6] = psum;
  __syncthreads();
  if (t == 0) ysum[(i * Bz + b) * Cz + c] = wsum[0] + wsum[1] + wsum[2] + wsum[3];
}

// ---------------------------------------------------------------------------
// C: squeeze-excite; sc = 1 + sigmoid(relu(ym@w1.T+b1)@w2.T+b2)
// grid 32 = (i,b), 128 thr
// ---------------------------------------------------------------------------
__global__ __launch_bounds__(128) void se_kernel(
    const float* __restrict__ ysum,
    const float* __restrict__ se_w1, const float* __restrict__ se_b1,
    const float* __restrict__ se_w2, const float* __restrict__ se_b2,
    float* __restrict__ sc) {
  const int i = blockIdx.x >> 3;
  const int b = blockIdx.x & 7;
  __shared__ float ym[Cz];
  __shared__ float h[CRz];
  const int t = threadIdx.x;
  const float* ys = ysum + (i * Bz + b) * Cz;
  for (int cc = t; cc < Cz; cc += 128) ym[cc] = ys[cc] * (1.f / Lz);
  __syncthreads();
  {
    const float* w1 = se_w1 + (size_t)i * CRz * Cz + (size_t)t * Cz;
    float s = se_b1[i * CRz + t];
    for (int cc = 0; cc < Cz; cc++) s += ym[cc] * w1[cc];
    h[t] = fmaxf(s, 0.f);
  }
  __syncthreads();
  for (int cc = t; cc < Cz; cc += 128) {
    const float* w2 = se_w2 + ((size_t)i * Cz + cc) * CRz;
    float s = se_b2[i * Cz + cc];
    for (int r = 0; r < CRz; r++) s += h[r] * w2[r];
    float wt = 1.f / (1.f + expf(-s));
    sc[(i * Bz + b) * Cz + cc] = 1.f + wt;
  }
}

// ---------------------------------------------------------------------------
// D: enhanced = LN_c( y[b,c,l]*sc[b,c] ), transposing (B,C,L)->(B,L,C)
// grid (L/16, B) per branch, 256 thr
// ---------------------------------------------------------------------------
__global__ __launch_bounds__(256) void ln_transpose_kernel(
    const float* __restrict__ ysrc, const float* __restrict__ sc,
    const float* __restrict__ g, const float* __restrict__ bb,
    float* __restrict__ edst) {
  __shared__ float tile[16][Cz + 1];
  const int l0 = blockIdx.x * 16;
  const int b = blockIdx.y;
  const int t = threadIdx.x;
  const float* yb = ysrc + (size_t)b * Cz * Lz;
  const float* scb = sc + b * Cz;
  for (int s = 0; s < 8; s++) {
    const int idx = s * 256 + t;
    const int c = idx >> 2;
    const int l4 = (idx & 3) * 4;
    float4 v = *(const float4*)(yb + (size_t)c * Lz + l0 + l4);
    const float scale = scb[c];
    tile[l4 + 0][c] = v.x * scale;
    tile[l4 + 1][c] = v.y * scale;
    tile[l4 + 2][c] = v.z * scale;
    tile[l4 + 3][c] = v.w * scale;
  }
  __syncthreads();
  const int wave = t >> 6, lane = t & 63;
  float* eb = edst + ((size_t)b * Lz + l0) * Cz;
  for (int r = wave; r < 16; r += 4) {
    float vals[8];
    float s1 = 0.f, s2 = 0.f;
#pragma unroll
    for (int j = 0; j < 8; j++) {
      float v = tile[r][lane + j * 64];
      vals[j] = v; s1 += v; s2 += v * v;
    }
    for (int off = 32; off > 0; off >>= 1) {
      s1 += __shfl_xor(s1, off, 64);
      s2 += __shfl_xor(s2, off, 64);
    }
    const float m = s1 * (1.f / Cz);
    const float var = s2 * (1.f / Cz) - m * m;
    const float inv = rsqrtf(var + EPSz);
#pragma unroll
    for (int j = 0; j < 8; j++) {
      const int cc = lane + j * 64;
      eb[(size_t)r * Cz + cc] = (vals[j] - m) * inv * g[cc] + bb[cc];
    }
  }
}

// ---------------------------------------------------------------------------
// E: score GEMM: Vi = e_i @ wv.T + bv; score_i = sum_d tanh(qc*Vi)*wg + bg
// grid (MT/64, 4), 256 thr; 64 rows x full DH=256
// ---------------------------------------------------------------------------
__global__ __launch_bounds__(256) void score_gemm_kernel(
    const float* __restrict__ e0, const float* __restrict__ e1,
    const float* __restrict__ e2, const float* __restrict__ e3,
    const float* __restrict__ wv, const float* __restrict__ bv,
    const float* __restrict__ qc, const float* __restrict__ wg,
    const float* __restrict__ bg, float* __restrict__ scores) {
  __shared__ float sA[16][68];
  __shared__ float sW[16][260];
  const int i = blockIdx.y;
  const float* E = (i == 0) ? e0 : (i == 1) ? e1 : (i == 2) ? e2 : e3;
  const int r0 = blockIdx.x * 64;
  const int t = threadIdx.x;
  const int tn = t & 15, tm = t >> 4;
  const int lrow = t >> 2, lk = (t & 3) * 4;
  float acc[4][16] = {};
  const float* ep = E + (size_t)(r0 + lrow) * Cz + lk;
  const float* wp = wv + (size_t)lrow * Cz + lk;
  for (int k0 = 0; k0 < Cz; k0 += 16) {
    float4 a4 = *(const float4*)(ep + k0);
    float4 q0 = *(const float4*)(wp + k0);
    float4 q1 = *(const float4*)(wp + (size_t)64 * Cz + k0);
    float4 q2 = *(const float4*)(wp + (size_t)128 * Cz + k0);
    float4 q3 = *(const float4*)(wp + (size_t)192 * Cz + k0);
    __syncthreads();
    sA[lk + 0][lrow] = a4.x; sA[lk + 1][lrow] = a4.y;
    sA[lk + 2][lrow] = a4.z; sA[lk + 3][lrow] = a4.w;
    sW[lk + 0][lrow] = q0.x; sW[lk + 1][lrow] = q0.y;
    sW[lk + 2][lrow] = q0.z; sW[lk + 3][lrow] = q0.w;
    sW[lk + 0][lrow + 64] = q1.x; sW[lk + 1][lrow + 64] = q1.y;
    sW[lk + 2][lrow + 64] = q1.z; sW[lk + 3][lrow + 64] = q1.w;
    sW[lk + 0][lrow + 128] = q2.x; sW[lk + 1][lrow + 128] = q2.y;
    sW[lk + 2][lrow + 128] = q2.z; sW[lk + 3][lrow + 128] = q2.w;
    sW[lk + 0][lrow + 192] = q3.x; sW[lk + 1][lrow + 192] = q3.y;
    sW[lk + 2][lrow + 192] = q3.z; sW[lk + 3][lrow + 192] = q3.w;
    __syncthreads();
#pragma unroll
    for (int k = 0; k < 16; k++) {
      float a[4];
      *(float4*)a = *(const float4*)&sA[k][tm * 4];
#pragma unroll
      for (int q = 0; q < 4; q++) {
        float w[4];
        *(float4*)w = *(const float4*)&sW[k][tn * 4 + q * 64];
#pragma unroll
        for (int m = 0; m < 4; m++)
#pragma unroll
          for (int r = 0; r < 4; r++) acc[m][q * 4 + r] += a[m] * w[r];
      }
    }
  }
  float part[4] = {0.f, 0.f, 0.f, 0.f};
#pragma unroll
  for (int q = 0; q < 4; q++) {
    const int n = tn * 4 + q * 64;
    float bv4[4], qc4[4], wg4[4];
    *(float4*)bv4 = *(const float4*)(bv + n);
    *(float4*)qc4 = *(const float4*)(qc + n);
    *(float4*)wg4 = *(const float4*)(wg + n);
#pragma unroll
    for (int r = 0; r < 4; r++)
#pragma unroll
      for (int m = 0; m < 4; m++)
        part[m] += tanhf(qc4[r] * (acc[m][q * 4 + r] + bv4[r])) * wg4[r];
  }
#pragma unroll
  for (int off = 1; off < 16; off <<= 1) {
#pragma unroll
    for (int m = 0; m < 4; m++) part[m] += __shfl_xor(part[m], off, 64);
  }
  if (tn == 0) {
    const float bgv = bg[0];
#pragma unroll
    for (int m = 0; m < 4; m++)
      scores[(size_t)i * MT + r0 + tm * 4 + m] = part[m] + bgv;
  }
}

// ---------------------------------------------------------------------------
// F: softmax over 4 branch scores + weighted combine of enhanced
// grid MT, 128 thr (4 floats each)
// ---------------------------------------------------------------------------
__global__ __launch_bounds__(128) void fuse_kernel(
    const float* __restrict__ e0, const float* __restrict__ e1,
    const float* __restrict__ e2, const float* __restrict__ e3,
    const float* __restrict__ scores, float* __restrict__ fused) {
  const int r = blockIdx.x;
  float s0 = scores[r], s1 = scores[MT + r], s2 = scores[2 * MT + r],
        s3 = scores[3 * MT + r];
  float mx = fmaxf(fmaxf(s0, s1), fmaxf(s2, s3));
  float x0 = expf(s0 - mx), x1 = expf(s1 - mx), x2 = expf(s2 - mx),
        x3 = expf(s3 - mx);
  float inv = 1.f / (x0 + x1 + x2 + x3);
  x0 *= inv; x1 *= inv; x2 *= inv; x3 *= inv;
  const int t = threadIdx.x;
  const size_t base = (size_t)r * Cz;
  float4 v0 = ((const float4*)(e0 + base))[t];
  float4 v1 = ((const float4*)(e1 + base))[t];
  float4 v2 = ((const float4*)(e2 + base))[t];
  float4 v3 = ((const float4*)(e3 + base))[t];
  float4 o;
  o.x = x0 * v0.x + x1 * v1.x + x2 * v2.x + x3 * v3.x;
  o.y = x0 * v0.y + x1 * v1.y + x2 * v2.y + x3 * v3.y;
  o.z = x0 * v0.z + x1 * v1.z + x2 * v2.z + x3 * v3.z;
  o.w = x0 * v0.w + x1 * v1.w + x2 * v2.w + x3 * v3.w;
  ((float4*)(fused + base))[t] = o;
}

// ---------------------------------------------------------------------------
// G: out = LN( LN(fused@op_w.T + op_b) + x )
// grid MT/32, 256 thr; block = 32 rows x full C=512
// ---------------------------------------------------------------------------
__global__ __launch_bounds__(256) void op_ln_kernel(
    const float* __restrict__ fusedp, const float* __restrict__ opw,
    const float* __restrict__ opb, const float* __restrict__ g1,
    const float* __restrict__ b1, const float* __restrict__ x,
    const float* __restrict__ g2, const float* __restrict__ b2,
    float* __restrict__ out) {
  __shared__ float sA[16][36];
  __shared__ float sW[16][516];
  const int r0 = blockIdx.x * 32;
  const int t = threadIdx.x;
  const int tn = t & 15, tm = t >> 4;
  const int lrow = t >> 2, lk = (t & 3) * 4;
  float acc[2][32] = {};
  const float* wp = opw + (size_t)lrow * Cz + lk;
  for (int k0 = 0; k0 < Cz; k0 += 16) {
    float4 a4 = make_float4(0.f, 0.f, 0.f, 0.f);
    if (t < 128)
      a4 = *(const float4*)(fusedp + (size_t)(r0 + (t >> 2)) * Cz + k0 +
                            (t & 3) * 4);
    float4 w4[8];
#pragma unroll
    for (int s = 0; s < 8; s++)
      w4[s] = *(const float4*)(wp + (size_t)s * 64 * Cz + k0);
    __syncthreads();
    if (t < 128) {
      sA[lk + 0][lrow] = a4.x; sA[lk + 1][lrow] = a4.y;
      sA[lk + 2][lrow] = a4.z; sA[lk + 3][lrow] = a4.w;
    }
#pragma unroll
    for (int s = 0; s < 8; s++) {
      sW[lk + 0][lrow + s * 64] = w4[s].x;
      sW[lk + 1][lrow + s * 64] = w4[s].y;
      sW[lk + 2][lrow + s * 64] = w4[s].z;
      sW[lk + 3][lrow + s * 64] = w4[s].w;
    }
    __syncthreads();
#pragma unroll
    for (int k = 0; k < 16; k++) {
      const float a0 = sA[k][tm * 2], a1 = sA[k][tm * 2 + 1];
#pragma unroll
      for (int q = 0; q < 8; q++) {
        float w[4];
        *(float4*)w = *(const float4*)&sW[k][tn * 4 + q * 64];
#pragma unroll
        for (int r = 0; r < 4; r++) {
          acc[0][q * 4 + r] += a0 * w[r];
          acc[1][q * 4 + r] += a1 * w[r];
        }
      }
    }
  }
#pragma unroll
  for (int j = 0; j < 2; j++) {
    const int row = r0 + tm * 2 + j;
    float s1 = 0.f, s2 = 0.f;
#pragma unroll
    for (int q = 0; q < 8; q++) {
      const int n = tn * 4 + q * 64;
      float ob[4];
      *(float4*)ob = *(const float4*)(opb + n);
#pragma unroll
      for (int r = 0; r < 4; r++) {
        float z = acc[j][q * 4 + r] + ob[r];
        acc[j][q * 4 + r] = z;
        s1 += z; s2 += z * z;
      }
    }
#pragma unroll
    for (int off = 1; off < 16; off <<= 1) {
      s1 += __shfl_xor(s1, off, 64);
      s2 += __shfl_xor(s2, off, 64);
    }
    const float m1 = s1 * (1.f / Cz);
    const float iv1 = rsqrtf(s2 * (1.f / Cz) - m1 * m1 + EPSz);
    s1 = 0.f; s2 = 0.f;
#pragma unroll
    for (int q = 0; q < 8; q++) {
      const int n = tn * 4 + q * 64;
      float gg[4], bb[4], xv[4];
      *(float4*)gg = *(const float4*)(g1 + n);
      *(float4*)bb = *(const float4*)(b1 + n);
      *(float4*)xv = *(const float4*)(x + (size_t)row * Cz + n);
#pragma unroll
      for (int r = 0; r < 4; r++) {
        float tt = (acc[j][q * 4 + r] - m1) * iv1 * gg[r] + bb[r] + xv[r];
        acc[j][q * 4 + r] = tt;
        s1 += tt; s2 += tt * tt;
      }
    }
#pragma unroll
    for (int off = 1; off < 16; off <<= 1) {
      s1 += __shfl_xor(s1, off, 64);
      s2 += __shfl_xor(s2, off, 64);
    }
    const float m2 = s1 * (1.f / Cz);
    const float iv2 = rsqrtf(s2 * (1.f / Cz) - m2 * m2 + EPSz);
#pragma unroll
    for (int q = 0; q < 8; q++) {
      const int n = tn * 4 + q * 64;
      float gg[4], bb[4];
      *(float4*)gg = *(const float4*)(g2 + n);
      *(float4*)bb = *(const float4*)(b2 + n);
      float4 o;
      o.x = (acc[j][q * 4 + 0] - m2) * iv2 * gg[0] + bb[0];
      o.y = (acc[j][q * 4 + 1] - m2) * iv2 * gg[1] + bb[1];
      o.z = (acc[j][q * 4 + 2] - m2) * iv2 * gg[2] + bb[2];
      o.w = (acc[j][q * 4 + 3] - m2) * iv2 * gg[3] + bb[3];
      *(float4*)(out + (size_t)row * Cz + n) = o;
    }
  }
}

// ---------------------------------------------------------------------------
extern "C" void kernel_launch(void* const* d_in, const int* in_sizes, int n_in,
                              void* d_out, int out_size, void* d_ws,
                              size_t ws_size, hipStream_t stream) {
  const float* x = (const float*)d_in[0];
  const float* pw_w = (const float*)d_in[1];
  const float* pw_b = (const float*)d_in[2];
  const float* pw_bn_g = (const float*)d_in[3];
  const float* pw_bn_b = (const float*)d_in[4];
  const float* pw_bn_m = (const float*)d_in[5];
  const float* pw_bn_v = (const float*)d_in[6];
  const float* dw_w0 = (const float*)d_in[7];
  const float* dw_w1 = (const float*)d_in[8];
  const float* dw_w2 = (const float*)d_in[9];
  const float* dw_w3 = (const float*)d_in[10];
  const float* dw_b = (const float*)d_in[11];
  const float* dw_bn_g = (const float*)d_in[12];
  const float* dw_bn_b = (const float*)d_in[13];
  const float* dw_bn_m = (const float*)d_in[14];
  const float* dw_bn_v = (const float*)d_in[15];
  const float* se_w1 = (const float*)d_in[16];
  const float* se_b1 = (const float*)d_in[17];
  const float* se_w2 = (const float*)d_in[18];
  const float* se_b2 = (const float*)d_in[19];
  const float* se_ln_g = (const float*)d_in[20];
  const float* se_ln_b = (const float*)d_in[21];
  // d_in[22] = df_ln_g (unused: LN of channel-constant rows -> bias only)
  const float* df_ln_b = (const float*)d_in[23];
  const float* wq = (const float*)d_in[24];
  const float* bq = (const float*)d_in[25];
  const float* wv = (const float*)d_in[26];
  const float* bv = (const float*)d_in[27];
  const float* wg = (const float*)d_in[28];
  const float* bg = (const float*)d_in[29];
  const float* op_w = (const float*)d_in[30];
  const float* op_b = (const float*)d_in[31];
  const float* op_ln_g = (const float*)d_in[32];
  const float* op_ln_b = (const float*)d_in[33];
  const float* fn_g = (const float*)d_in[34];
  const float* fn_b = (const float*)d_in[35];
  float* out = (float*)d_out;

  float* ws = (float*)d_ws;
  const size_t NBL = (size_t)Bz * Cz * Lz;  // 8388608 floats
  float* xpw = ws;                          // [NBL]; reused as `fused` later
  float* y = ws + NBL;                      // [4*NBL]
  float* spare = ws + 5 * NBL;              // [NBL]
  // enhanced buffers: reuse dead y slots (sequential branch processing)
  float* e[4] = {spare, y, y + NBL, y + 2 * NBL};
  float* smallb = ws + 6 * NBL;
  float* ysum = smallb;                 // 16384
  float* scv = smallb + 16384;          // 16384
  float* scores = smallb + 32768;       // 65536
  float* pwA = smallb + 98304;          // 512
  float* pwB = pwA + 512;               // 512
  float* dwA = pwB + 512;               // 2048
  float* dwB = dwA + 2048;              // 2048
  float* qc = dwB + 2048;               // 256

  prep_kernel<<<6, 256, 0, stream>>>(pw_b, pw_bn_g, pw_bn_b, pw_bn_m, pw_bn_v,
                                     dw_b, dw_bn_g, dw_bn_b, dw_bn_m, dw_bn_v,
                                     df_ln_b, wq, bq, pwA, pwB, dwA, dwB, qc);

  pw_gemm_kernel<<<dim3(Lz / 64, Cz / 64, Bz), 256, 0, stream>>>(
      x, pw_w, pwA, pwB, xpw);

  dw_conv_kernel<<<4 * Bz * Cz, 256, 0, stream>>>(xpw, dw_w0, dw_w1, dw_w2,
                                                  dw_w3, dwA, dwB, y, ysum);

  se_kernel<<<32, 128, 0, stream>>>(ysum, se_w1, se_b1, se_w2, se_b2, scv);

  for (int i = 0; i < 4; i++) {
    ln_transpose_kernel<<<dim3(Lz / 16, Bz), 256, 0, stream>>>(
        y + (size_t)i * NBL, scv + (size_t)i * Bz * Cz, se_ln_g + i * Cz,
        se_ln_b + i * Cz, e[i]);
  }

  score_gemm_kernel<<<dim3(MT / 64, 4), 256, 0, stream>>>(
      e[0], e[1], e[2], e[3], wv, bv, qc, wg, bg, scores);

  fuse_kernel<<<MT, 128, 0, stream>>>(e[0], e[1], e[2], e[3], scores, xpw);

  op_ln_kernel<<<MT / 32, 256, 0, stream>>>(xpw, op_w, op_b, op_ln_g, op_ln_b,
                                            x, fn_g, fn_b, out);
}